// Round 1
// baseline (1713.898 us; speedup 1.0000x reference)
//
#include <hip/hip_runtime.h>
#include <hip/hip_bf16.h>

#define DEV static __device__ __forceinline__

typedef short s16x8 __attribute__((ext_vector_type(8)));
typedef float f32x4 __attribute__((ext_vector_type(4)));
typedef unsigned short u16;

constexpr int Bn = 64, Pn = 196, ENCn = 2048, EMBn = 512, DECn = 512, ATTn = 512;
constexpr int VOCABn = 10000, Sn = 20;

DEV u16 f2bf(float x) {
  union { float f; unsigned u; } v; v.f = x;
  unsigned r = v.u + 0x7fffu + ((v.u >> 16) & 1u);
  return (u16)(r >> 16);
}
DEV float bf2f(u16 b) {
  union { unsigned u; float f; } v; v.u = ((unsigned)b) << 16;
  return v.f;
}
DEV float sigm(float x) { return 1.f / (1.f + __expf(-x)); }

DEV s16x8 ld8(const u16* p) { return *reinterpret_cast<const s16x8*>(p); }
DEV s16x8 ld8(const float* p) {
  s16x8 r;
#pragma unroll
  for (int j = 0; j < 8; j++) r[j] = (short)f2bf(p[j]);
  return r;
}
DEV f32x4 mfma(s16x8 a, s16x8 b, f32x4 c) {
  return __builtin_amdgcn_mfma_f32_16x16x32_bf16(a, b, c, 0, 0, 0);
}

// ---------------- conversion f32 -> bf16, 8 elements/thread ----------------
__global__ void k_cvt8(const float* __restrict__ src, u16* __restrict__ dst, int n8) {
  int i = blockIdx.x * 256 + threadIdx.x;
  int stride = gridDim.x * 256;
  for (; i < n8; i += stride) {
    const float4* s = (const float4*)(src + (size_t)i * 8);
    float4 a = s[0], b = s[1];
    s16x8 o;
    o[0] = (short)f2bf(a.x); o[1] = (short)f2bf(a.y);
    o[2] = (short)f2bf(a.z); o[3] = (short)f2bf(a.w);
    o[4] = (short)f2bf(b.x); o[5] = (short)f2bf(b.y);
    o[6] = (short)f2bf(b.z); o[7] = (short)f2bf(b.w);
    *(s16x8*)(dst + (size_t)i * 8) = o;
  }
}

// ---------------- mean over P ----------------
__global__ void k_avg(const float* __restrict__ feat, float* __restrict__ avg) {
  int idx = blockIdx.x * 256 + threadIdx.x;   // B*ENC = 131072
  int b = idx >> 11, e = idx & 2047;
  const float* p = feat + (size_t)b * Pn * ENCn + e;
  float s = 0.f;
  for (int k = 0; k < Pn; k++) s += p[(size_t)k * ENCn];
  avg[idx] = s * (1.0f / 196.0f);
}

// ---------------- generic skinny GEMM: C[64,N] = act(A[64,K] @ W[N,K]^T + b) ----
// grid = N/16 blocks, 256 threads = 4 waves = 4 m-tiles sharing one n-tile.
template<typename TA, typename TW, int ACT, int K>
__global__ __launch_bounds__(256) void k_lin64(
    const TA* __restrict__ A, const TW* __restrict__ W,
    const float* __restrict__ bias1, const float* __restrict__ bias2,
    float* __restrict__ outF, size_t ldo, u16* __restrict__ outB) {
  int wid = threadIdx.x >> 6, lane = threadIdx.x & 63;
  int r = lane & 15, hi = lane >> 4;
  int n0 = blockIdx.x * 16;
  const TA* ap = A + (size_t)(wid * 16 + r) * K + hi * 8;
  const TW* wp = W + (size_t)(n0 + r) * K + hi * 8;
  f32x4 acc = {0.f, 0.f, 0.f, 0.f};
  for (int k = 0; k < K; k += 32) acc = mfma(ld8(ap + k), ld8(wp + k), acc);
  int col = n0 + r;
  float bb = (bias1 ? bias1[col] : 0.f) + (bias2 ? bias2[col] : 0.f);
#pragma unroll
  for (int j = 0; j < 4; j++) {
    int row = wid * 16 + hi * 4 + j;
    float v = acc[j] + bb;
    if (ACT) v = fmaxf(v, 0.f);
    if (outF) outF[(size_t)row * ldo + col] = v;
    if (outB) outB[(size_t)row * DECn + col] = f2bf(v);
  }
}

// ---------------- enc_proj: [12544,512] = A[12544,2048] @ W[512,2048]^T + b ----
// 64x64 block tile, LDS-staged, 4 waves each 32x32 quadrant.
__global__ __launch_bounds__(256) void k_encproj(
    const u16* __restrict__ Abf, const u16* __restrict__ Wbf,
    const float* __restrict__ bias, float* __restrict__ out) {
  __shared__ u16 As[64][40];
  __shared__ u16 Bs[64][40];
  int m0 = blockIdx.y * 64, n0 = blockIdx.x * 64;
  int tid = threadIdx.x;
  int lrow = tid >> 2, lc = (tid & 3) * 8;
  int wid = tid >> 6, lane = tid & 63, r = lane & 15, hi = lane >> 4;
  int qm = (wid >> 1) * 32, qn = (wid & 1) * 32;
  f32x4 acc[2][2] = {};
  const u16* ag = Abf + (size_t)(m0 + lrow) * 2048 + lc;
  const u16* bg = Wbf + (size_t)(n0 + lrow) * 2048 + lc;
  for (int k0 = 0; k0 < 2048; k0 += 32) {
    *(s16x8*)&As[lrow][lc] = *(const s16x8*)(ag + k0);
    *(s16x8*)&Bs[lrow][lc] = *(const s16x8*)(bg + k0);
    __syncthreads();
    s16x8 af[2], bf[2];
#pragma unroll
    for (int mm = 0; mm < 2; mm++) af[mm] = *(const s16x8*)&As[qm + mm * 16 + r][hi * 8];
#pragma unroll
    for (int nn = 0; nn < 2; nn++) bf[nn] = *(const s16x8*)&Bs[qn + nn * 16 + r][hi * 8];
#pragma unroll
    for (int mm = 0; mm < 2; mm++)
#pragma unroll
      for (int nn = 0; nn < 2; nn++)
        acc[mm][nn] = mfma(af[mm], bf[nn], acc[mm][nn]);
    __syncthreads();
  }
#pragma unroll
  for (int mm = 0; mm < 2; mm++)
#pragma unroll
    for (int nn = 0; nn < 2; nn++) {
      int col = n0 + qn + nn * 16 + r;
      float bb = bias[col];
#pragma unroll
      for (int j = 0; j < 4; j++) {
        int row = m0 + qm + mm * 16 + hi * 4 + j;
        out[(size_t)row * 512 + col] = acc[mm][nn][j] + bb;
      }
    }
}

// ---------------- attention scores: e[b,p] = V . tanh(encp[b,p,:]+decp[b,:]) + Vb
// wave per (b,p); grid (49, 64), 256 thr = 4 waves.
__global__ __launch_bounds__(256) void k_attn(
    const float* __restrict__ encp, const float* __restrict__ decp,
    const float* __restrict__ Vw, const float* __restrict__ Vb,
    float* __restrict__ e) {
  int wid = threadIdx.x >> 6, lane = threadIdx.x & 63;
  int p = blockIdx.x * 4 + wid;
  int b = blockIdx.y;
  const float* ep = encp + ((size_t)b * Pn + p) * ATTn;
  const float* dp = decp + (size_t)b * ATTn;
  float s = 0.f;
#pragma unroll
  for (int c = 0; c < 2; c++) {
    int a = c * 256 + lane * 4;
    float4 ev = *(const float4*)(ep + a);
    float4 dv = *(const float4*)(dp + a);
    float4 vv = *(const float4*)(Vw + a);
    s += vv.x * tanhf(ev.x + dv.x);
    s += vv.y * tanhf(ev.y + dv.y);
    s += vv.z * tanhf(ev.z + dv.z);
    s += vv.w * tanhf(ev.w + dv.w);
  }
  for (int m = 32; m; m >>= 1) s += __shfl_xor(s, m);
  if (lane == 0) e[(size_t)b * Pn + p] = s + Vb[0];
}

// ---------------- softmax (recomputed per block) + ctx chunk -> bf16 ----------
// grid (4, 64): chunk of 512 enc dims x one b. 256 threads.
__global__ __launch_bounds__(256) void k_ctx(
    const float* __restrict__ e, const u16* __restrict__ featbf,
    u16* __restrict__ ctxbf) {
  __shared__ float sw[Pn];
  __shared__ float red[256];
  int b = blockIdx.y, chunk = blockIdx.x, tid = threadIdx.x;
  float ev = (tid < Pn) ? e[(size_t)b * Pn + tid] : -3.0e38f;
  red[tid] = ev; __syncthreads();
  for (int s = 128; s > 0; s >>= 1) { if (tid < s) red[tid] = fmaxf(red[tid], red[tid + s]); __syncthreads(); }
  float m = red[0]; __syncthreads();
  float ex = (tid < Pn) ? __expf(ev - m) : 0.f;
  red[tid] = ex; __syncthreads();
  for (int s = 128; s > 0; s >>= 1) { if (tid < s) red[tid] += red[tid + s]; __syncthreads(); }
  float inv = 1.f / red[0];
  if (tid < Pn) sw[tid] = ex * inv;
  __syncthreads();
  int e0 = chunk * 512 + tid * 2;
  float ax = 0.f, ay = 0.f;
  const u16* fp = featbf + (size_t)b * Pn * ENCn + e0;
  for (int p = 0; p < Pn; p++) {
    float w = sw[p];
    unsigned v = *(const unsigned*)(fp + (size_t)p * ENCn);
    ax += w * bf2f((u16)(v & 0xffffu));
    ay += w * bf2f((u16)(v >> 16));
  }
  unsigned pk = (unsigned)f2bf(ax) | ((unsigned)f2bf(ay) << 16);
  *(unsigned*)(ctxbf + (size_t)b * ENCn + e0) = pk;
}

// ---------------- gates GEMM: [64,2048] = [ctx|emb|h] @ [W_ih|W_hh]^T + b -----
// grid 128 blocks, 4 waves = 4 m-tiles.
__global__ __launch_bounds__(256) void k_gates(
    const u16* __restrict__ ctxbf, const float* __restrict__ embw,
    const int* __restrict__ caps, int t, const u16* __restrict__ hbf,
    const u16* __restrict__ Wih, const u16* __restrict__ Whh,
    const float* __restrict__ bih, const float* __restrict__ bhh,
    float* __restrict__ gates) {
  int wid = threadIdx.x >> 6, lane = threadIdx.x & 63;
  int r = lane & 15, hi = lane >> 4;
  int n0 = blockIdx.x * 16;
  int brow = wid * 16 + r;
  f32x4 acc = {0.f, 0.f, 0.f, 0.f};
  const u16* arow = ctxbf + (size_t)brow * ENCn + hi * 8;
  const u16* wrow = Wih + (size_t)(n0 + r) * 2560 + hi * 8;
  for (int k = 0; k < 2048; k += 32) acc = mfma(ld8(arow + k), ld8(wrow + k), acc);
  int id = caps[brow * Sn + t];
  const float* erow = embw + (size_t)id * EMBn + hi * 8;
  for (int k = 0; k < 512; k += 32) acc = mfma(ld8(erow + k), ld8(wrow + 2048 + k), acc);
  const u16* hrow = hbf + (size_t)brow * DECn + hi * 8;
  const u16* w2 = Whh + (size_t)(n0 + r) * 512 + hi * 8;
  for (int k = 0; k < 512; k += 32) acc = mfma(ld8(hrow + k), ld8(w2 + k), acc);
  int col = n0 + r;
  float bb = bih[col] + bhh[col];
#pragma unroll
  for (int j = 0; j < 4; j++) {
    int row = wid * 16 + hi * 4 + j;
    gates[(size_t)row * 2048 + col] = acc[j] + bb;
  }
}

// ---------------- LSTM pointwise + fused dec_proj for next step ---------------
// grid 64 blocks (b), 512 threads (d / n).
__global__ __launch_bounds__(512) void k_lstm(
    const float* __restrict__ gates, float* __restrict__ c,
    u16* __restrict__ hbf, const u16* __restrict__ wdecbf,
    const float* __restrict__ wdec_b, float* __restrict__ decp) {
  __shared__ float sh[DECn];
  int b = blockIdx.x, d = threadIdx.x;
  const float* g = gates + (size_t)b * 2048;
  float gi = g[d], gf = g[512 + d], gg = g[1024 + d], go = g[1536 + d];
  float cn = sigm(gf) * c[(size_t)b * DECn + d] + sigm(gi) * tanhf(gg);
  float hn = sigm(go) * tanhf(cn);
  c[(size_t)b * DECn + d] = cn;
  hbf[(size_t)b * DECn + d] = f2bf(hn);
  sh[d] = hn;
  __syncthreads();
  const u16* wr = wdecbf + (size_t)d * DECn;
  float acc = 0.f;
  for (int k = 0; k < DECn; k += 8) {
    s16x8 w8 = *(const s16x8*)(wr + k);
#pragma unroll
    for (int j = 0; j < 8; j++) acc += bf2f((u16)w8[j]) * sh[k + j];
  }
  decp[(size_t)b * DECn + d] = acc + wdec_b[d];
}

// ============================================================================
extern "C" void kernel_launch(void* const* d_in, const int* in_sizes, int n_in,
                              void* d_out, int out_size, void* d_ws, size_t ws_size,
                              hipStream_t stream) {
  const float* image_feat = (const float*)d_in[0];
  const int*   captions   = (const int*)d_in[1];
  const float* wenc_w = (const float*)d_in[2];
  const float* wenc_b = (const float*)d_in[3];
  const float* wdec_w = (const float*)d_in[4];
  const float* wdec_b = (const float*)d_in[5];
  const float* V_w    = (const float*)d_in[6];
  const float* V_b    = (const float*)d_in[7];
  const float* embed_w = (const float*)d_in[8];
  const float* h0_w = (const float*)d_in[9];
  const float* h0_b = (const float*)d_in[10];
  const float* c0_w = (const float*)d_in[11];
  const float* c0_b = (const float*)d_in[12];
  const float* W_ih = (const float*)d_in[13];
  const float* b_ih = (const float*)d_in[14];
  const float* W_hh = (const float*)d_in[15];
  const float* b_hh = (const float*)d_in[16];
  const float* fc_w = (const float*)d_in[17];
  const float* fc_b = (const float*)d_in[18];
  float* out = (float*)d_out;

  char* w = (char*)d_ws;
  auto alloc = [&](size_t bytes) { void* p = (void*)w; w += (bytes + 255) & ~(size_t)255; return p; };
  u16* if_bf   = (u16*)alloc(sizeof(u16) * (size_t)Bn * Pn * ENCn);
  u16* wenc_bf = (u16*)alloc(sizeof(u16) * (size_t)ATTn * ENCn);
  u16* wdec_bf = (u16*)alloc(sizeof(u16) * (size_t)ATTn * DECn);
  u16* Wih_bf  = (u16*)alloc(sizeof(u16) * (size_t)2048 * 2560);
  u16* Whh_bf  = (u16*)alloc(sizeof(u16) * (size_t)2048 * 512);
  u16* fcw_bf  = (u16*)alloc(sizeof(u16) * (size_t)VOCABn * DECn);
  u16* h_bf    = (u16*)alloc(sizeof(u16) * (size_t)Bn * DECn);
  u16* ctx_bf  = (u16*)alloc(sizeof(u16) * (size_t)Bn * ENCn);
  float* avg   = (float*)alloc(sizeof(float) * (size_t)Bn * ENCn);
  float* encp  = (float*)alloc(sizeof(float) * (size_t)Bn * Pn * ATTn);
  float* decp  = (float*)alloc(sizeof(float) * (size_t)Bn * ATTn);
  float* evec  = (float*)alloc(sizeof(float) * (size_t)Bn * Pn);
  float* gates = (float*)alloc(sizeof(float) * (size_t)Bn * 2048);
  float* cbuf  = (float*)alloc(sizeof(float) * (size_t)Bn * DECn);

  auto cvt = [&](const float* s, u16* d, size_t n) {
    int n8 = (int)(n / 8);
    int blocks = (n8 + 255) / 256; if (blocks > 2048) blocks = 2048;
    k_cvt8<<<blocks, 256, 0, stream>>>(s, d, n8);
  };
  cvt(image_feat, if_bf, (size_t)Bn * Pn * ENCn);
  cvt(wenc_w, wenc_bf, (size_t)ATTn * ENCn);
  cvt(wdec_w, wdec_bf, (size_t)ATTn * DECn);
  cvt(W_ih, Wih_bf, (size_t)2048 * 2560);
  cvt(W_hh, Whh_bf, (size_t)2048 * 512);
  cvt(fc_w, fcw_bf, (size_t)VOCABn * DECn);

  k_avg<<<512, 256, 0, stream>>>(image_feat, avg);
  k_encproj<<<dim3(8, 196), 256, 0, stream>>>(if_bf, wenc_bf, wenc_b, encp);
  // h0 = relu(avg @ h0_w^T + b) -> bf16 only; c0 -> f32 only
  k_lin64<float, float, 1, 2048><<<32, 256, 0, stream>>>(avg, h0_w, h0_b, nullptr, nullptr, 0, h_bf);
  k_lin64<float, float, 1, 2048><<<32, 256, 0, stream>>>(avg, c0_w, c0_b, nullptr, cbuf, 512, nullptr);
  // dec_proj(h0)
  k_lin64<u16, u16, 0, 512><<<32, 256, 0, stream>>>(h_bf, wdec_bf, wdec_b, nullptr, decp, 512, nullptr);

  for (int t = 0; t < Sn; t++) {
    k_attn<<<dim3(49, Bn), 256, 0, stream>>>(encp, decp, V_w, V_b, evec);
    k_ctx<<<dim3(4, Bn), 256, 0, stream>>>(evec, if_bf, ctx_bf);
    k_gates<<<128, 256, 0, stream>>>(ctx_bf, embed_w, captions, t, h_bf,
                                     Wih_bf, Whh_bf, b_ih, b_hh, gates);
    k_lstm<<<Bn, 512, 0, stream>>>(gates, cbuf, h_bf, wdec_bf, wdec_b, decp);
    k_lin64<u16, u16, 0, 512><<<625, 256, 0, stream>>>(
        h_bf, fcw_bf, fc_b, nullptr, out + (size_t)t * VOCABn, (size_t)Sn * VOCABn, nullptr);
  }
}